// Round 2
// baseline (274.702 us; speedup 1.0000x reference)
//
#include <hip/hip_runtime.h>

// Problem constants
#define NN 8192
#define EE 65536
#define T1_COLS 480   // 8*48 W-slices + 48 bias-matrix + 48 root1
#define T2_COLS 320   // 8*32 W-slices + 32 bias-matrix + 32 root2

// ---------------------------------------------------------------------------
// k_pre: (a) zero agg1/agg2/deg (contiguous, 663552 floats)
//        (b) pack Wp1[64][480]: c<384 -> w1[f*3072+i*48+o] (f=c/48,o=c%48)
//                               384..431 -> b1[i*48+(c-384)]
//                               432..479 -> r1[i*48+(c-432)]
//        (c) pack Wp2[48][320]: c<256 -> w2[f*1536+i*32+o]
//                               256..287 -> b2[i*32+..], 288..319 -> r2[i*32+..]
// grid 828*256 = 211968 threads = 165888 zero-float4 + 46080 pack elems
// ---------------------------------------------------------------------------
__global__ __launch_bounds__(256) void k_pre(const float* __restrict__ w1,
                                             const float* __restrict__ b1,
                                             const float* __restrict__ r1,
                                             const float* __restrict__ w2,
                                             const float* __restrict__ b2,
                                             const float* __restrict__ r2,
                                             float* __restrict__ Wp1,
                                             float* __restrict__ Wp2,
                                             float* __restrict__ zbase) {
    int t = blockIdx.x * 256 + threadIdx.x;
    if (t < 165888) {
        ((float4*)zbase)[t] = make_float4(0.f, 0.f, 0.f, 0.f);
        return;
    }
    int p = t - 165888;
    if (p < 30720) {
        int i = p / 480, c = p - i * 480;
        float v;
        if (c < 384) { int f = c / 48, o = c - f * 48; v = w1[f * 3072 + i * 48 + o]; }
        else if (c < 432) v = b1[i * 48 + (c - 384)];
        else              v = r1[i * 48 + (c - 432)];
        Wp1[p] = v;
    } else {
        p -= 30720;
        int i = p / 320, c = p - i * 320;
        float v;
        if (c < 256) { int f = c >> 5, o = c & 31; v = w2[f * 1536 + i * 32 + o]; }
        else if (c < 288) v = b2[i * 32 + (c - 256)];
        else              v = r2[i * 32 + (c - 288)];
        Wp2[p] = v;
    }
}

// ---------------------------------------------------------------------------
// k_T1: T1[n][c] = sum_i x[n][i] * Wp1[i][c].  lane = node, x in VGPRs,
// weights wave-uniform (scalar loads). 1920 wave-jobs = 128 node-tiles x 15
// col-groups of 32; grid 480 blocks x 256 (4 waves).
// ---------------------------------------------------------------------------
__global__ __launch_bounds__(256) void k_T1(const float* __restrict__ x,
                                            const float* __restrict__ Wp,
                                            float* __restrict__ T1) {
    const int j = blockIdx.x * 4 + (threadIdx.x >> 6);
    const int lane = threadIdx.x & 63;
    const int nt = j / 15, grp = j - nt * 15;
    const int n = nt * 64 + lane;
    float xr[64];
    const float4* xp = (const float4*)(x + (size_t)n * 64);
#pragma unroll
    for (int q = 0; q < 16; q++) {
        float4 v = xp[q];
        xr[4 * q] = v.x; xr[4 * q + 1] = v.y; xr[4 * q + 2] = v.z; xr[4 * q + 3] = v.w;
    }
#pragma unroll
    for (int ch = 0; ch < 2; ch++) {
        const int c0 = grp * 32 + ch * 16;
        const float* wr = Wp + c0;
        float acc[16];
#pragma unroll
        for (int c = 0; c < 16; c++) acc[c] = 0.f;
#pragma unroll
        for (int i = 0; i < 64; i++) {
            float xv = xr[i];
#pragma unroll
            for (int c = 0; c < 16; c++) acc[c] += xv * wr[i * 480 + c];
        }
        float4* o4 = (float4*)(T1 + (size_t)n * 480 + c0);
#pragma unroll
        for (int q = 0; q < 4; q++)
            o4[q] = make_float4(acc[4 * q], acc[4 * q + 1], acc[4 * q + 2], acc[4 * q + 3]);
    }
}

// ---------------------------------------------------------------------------
// k_T2: same structure, K=48, 320 cols, with h1 = relu(agg1 + root1part +
// bias1) computed on the fly (k_h1 fused away). 1280 jobs = 128 x 10 groups.
// ---------------------------------------------------------------------------
__global__ __launch_bounds__(256) void k_T2(const float* __restrict__ agg1,
                                            const float* __restrict__ T1,
                                            const float* __restrict__ bias1,
                                            const float* __restrict__ Wp,
                                            float* __restrict__ T2) {
    const int j = blockIdx.x * 4 + (threadIdx.x >> 6);
    const int lane = threadIdx.x & 63;
    const int nt = j / 10, grp = j - nt * 10;
    const int n = nt * 64 + lane;
    float xr[48];
    const float4* ap = (const float4*)(agg1 + (size_t)n * 48);
    const float4* rp = (const float4*)(T1 + (size_t)n * 480 + 432);
#pragma unroll
    for (int q = 0; q < 12; q++) {
        float4 a = ap[q];
        float4 r = rp[q];
        float4 b = *(const float4*)(bias1 + 4 * q);
        xr[4 * q]     = fmaxf(a.x + r.x + b.x, 0.f);
        xr[4 * q + 1] = fmaxf(a.y + r.y + b.y, 0.f);
        xr[4 * q + 2] = fmaxf(a.z + r.z + b.z, 0.f);
        xr[4 * q + 3] = fmaxf(a.w + r.w + b.w, 0.f);
    }
#pragma unroll
    for (int ch = 0; ch < 2; ch++) {
        const int c0 = grp * 32 + ch * 16;
        const float* wr = Wp + c0;
        float acc[16];
#pragma unroll
        for (int c = 0; c < 16; c++) acc[c] = 0.f;
#pragma unroll
        for (int i = 0; i < 48; i++) {
            float xv = xr[i];
#pragma unroll
            for (int c = 0; c < 16; c++) acc[c] += xv * wr[i * 320 + c];
        }
        float4* o4 = (float4*)(T2 + (size_t)n * 320 + c0);
#pragma unroll
        for (int q = 0; q < 4; q++)
            o4[q] = make_float4(acc[4 * q], acc[4 * q + 1], acc[4 * q + 2], acc[4 * q + 3]);
    }
}

// ---------------------------------------------------------------------------
// k_edge1: thread per (edge, 4 outputs). 12 threads/edge, float4 gathers.
// msg4 = T1[s][384+o4*4..] + sum_f ea[f]*T1[s][f*48+o4*4..]; atomic into agg1.
// ---------------------------------------------------------------------------
__global__ __launch_bounds__(256) void k_edge1(const int* __restrict__ ei,
                                               const float* __restrict__ ea,
                                               const float* __restrict__ T1,
                                               float* __restrict__ agg1) {
    int idx = blockIdx.x * 256 + threadIdx.x;
    int e = idx / 12, o4 = idx - e * 12;
    if (e >= EE) return;
    int s = ei[e], d = ei[EE + e];
    const float* t = T1 + (size_t)s * 480 + o4 * 4;
    const float4* a4 = (const float4*)(ea + (size_t)e * 8);
    float4 a0 = a4[0], a1 = a4[1];
    float4 m = *(const float4*)(t + 384);
    float4 w;
    w = *(const float4*)(t + 0 * 48); m.x += a0.x * w.x; m.y += a0.x * w.y; m.z += a0.x * w.z; m.w += a0.x * w.w;
    w = *(const float4*)(t + 1 * 48); m.x += a0.y * w.x; m.y += a0.y * w.y; m.z += a0.y * w.z; m.w += a0.y * w.w;
    w = *(const float4*)(t + 2 * 48); m.x += a0.z * w.x; m.y += a0.z * w.y; m.z += a0.z * w.z; m.w += a0.z * w.w;
    w = *(const float4*)(t + 3 * 48); m.x += a0.w * w.x; m.y += a0.w * w.y; m.z += a0.w * w.z; m.w += a0.w * w.w;
    w = *(const float4*)(t + 4 * 48); m.x += a1.x * w.x; m.y += a1.x * w.y; m.z += a1.x * w.z; m.w += a1.x * w.w;
    w = *(const float4*)(t + 5 * 48); m.x += a1.y * w.x; m.y += a1.y * w.y; m.z += a1.y * w.z; m.w += a1.y * w.w;
    w = *(const float4*)(t + 6 * 48); m.x += a1.z * w.x; m.y += a1.z * w.y; m.z += a1.z * w.z; m.w += a1.z * w.w;
    w = *(const float4*)(t + 7 * 48); m.x += a1.w * w.x; m.y += a1.w * w.y; m.z += a1.w * w.z; m.w += a1.w * w.w;
    float* ag = agg1 + (size_t)d * 48 + o4 * 4;
    atomicAdd(ag + 0, m.x);
    atomicAdd(ag + 1, m.y);
    atomicAdd(ag + 2, m.z);
    atomicAdd(ag + 3, m.w);
}

// k_edge2: 8 threads/edge + degree count.
__global__ __launch_bounds__(256) void k_edge2(const int* __restrict__ ei,
                                               const float* __restrict__ ea,
                                               const float* __restrict__ T2,
                                               float* __restrict__ agg2,
                                               float* __restrict__ deg) {
    int idx = blockIdx.x * 256 + threadIdx.x;
    int e = idx >> 3, o4 = idx & 7;
    if (e >= EE) return;
    int s = ei[e], d = ei[EE + e];
    const float* t = T2 + (size_t)s * 320 + o4 * 4;
    const float4* a4 = (const float4*)(ea + (size_t)e * 8);
    float4 a0 = a4[0], a1 = a4[1];
    float4 m = *(const float4*)(t + 256);
    float4 w;
    w = *(const float4*)(t + 0 * 32); m.x += a0.x * w.x; m.y += a0.x * w.y; m.z += a0.x * w.z; m.w += a0.x * w.w;
    w = *(const float4*)(t + 1 * 32); m.x += a0.y * w.x; m.y += a0.y * w.y; m.z += a0.y * w.z; m.w += a0.y * w.w;
    w = *(const float4*)(t + 2 * 32); m.x += a0.z * w.x; m.y += a0.z * w.y; m.z += a0.z * w.z; m.w += a0.z * w.w;
    w = *(const float4*)(t + 3 * 32); m.x += a0.w * w.x; m.y += a0.w * w.y; m.z += a0.w * w.z; m.w += a0.w * w.w;
    w = *(const float4*)(t + 4 * 32); m.x += a1.x * w.x; m.y += a1.x * w.y; m.z += a1.x * w.z; m.w += a1.x * w.w;
    w = *(const float4*)(t + 5 * 32); m.x += a1.y * w.x; m.y += a1.y * w.y; m.z += a1.y * w.z; m.w += a1.y * w.w;
    w = *(const float4*)(t + 6 * 32); m.x += a1.z * w.x; m.y += a1.z * w.y; m.z += a1.z * w.z; m.w += a1.z * w.w;
    w = *(const float4*)(t + 7 * 32); m.x += a1.w * w.x; m.y += a1.w * w.y; m.z += a1.w * w.z; m.w += a1.w * w.w;
    float* ag = agg2 + (size_t)d * 32 + o4 * 4;
    atomicAdd(ag + 0, m.x);
    atomicAdd(ag + 1, m.y);
    atomicAdd(ag + 2, m.z);
    atomicAdd(ag + 3, m.w);
    if (o4 == 0) atomicAdd(deg + d, 1.0f);
}

// ---------------------------------------------------------------------------
// k_post: h2 = relu(agg2 + root2part + bias2); hmu=h2@mu_w; hls=h2@ls_w;
// out initialized with self-loop term + bias; dinv stored.
// ---------------------------------------------------------------------------
__global__ __launch_bounds__(256) void k_post(const float* __restrict__ agg2,
                                              const float* __restrict__ T2,
                                              const float* __restrict__ bias2,
                                              const float* __restrict__ mu_w,
                                              const float* __restrict__ mu_b,
                                              const float* __restrict__ ls_w,
                                              const float* __restrict__ ls_b,
                                              const float* __restrict__ deg,
                                              float* __restrict__ hmu,
                                              float* __restrict__ hls,
                                              float* __restrict__ dinv,
                                              float* __restrict__ out) {
    __shared__ float h2s[8][32];
    const int n0 = blockIdx.x * 8;
    const int lid = threadIdx.x >> 5;
    const int o = threadIdx.x & 31;
    const int n = n0 + lid;
    float v = agg2[(size_t)n * 32 + o] + T2[(size_t)n * 320 + 288 + o] + bias2[o];
    h2s[lid][o] = v > 0.f ? v : 0.f;
    __syncthreads();
    const float* wm = (o < 16) ? mu_w : ls_w;
    const float* bb = (o < 16) ? mu_b : ls_b;
    const int oo = o & 15;
    float acc = 0.f;
#pragma unroll
    for (int i = 0; i < 32; i++) acc += h2s[lid][i] * wm[i * 16 + oo];
    float d = deg[n] + 1.0f;
    float di = rsqrtf(d);
    if (o == 0) dinv[n] = di;
    float init = acc / d + bb[oo];
    if (o < 16) {
        hmu[(size_t)n * 16 + oo] = acc;
        out[(size_t)n * 16 + oo] = init;
    } else {
        hls[(size_t)n * 16 + oo] = acc;
        out[(size_t)NN * 16 + (size_t)n * 16 + oo] = init;
    }
}

// k_gcn_edge: 4 threads/edge, float4 gathers, 8 atomics each.
__global__ __launch_bounds__(256) void k_gcn_edge(const int* __restrict__ ei,
                                                  const float* __restrict__ hmu,
                                                  const float* __restrict__ hls,
                                                  const float* __restrict__ dinv,
                                                  float* __restrict__ out) {
    int idx = blockIdx.x * 256 + threadIdx.x;
    int e = idx >> 2, o4 = idx & 3;
    if (e >= EE) return;
    int s = ei[e], d = ei[EE + e];
    float norm = dinv[s] * dinv[d];
    float4 m = *(const float4*)(hmu + (size_t)s * 16 + o4 * 4);
    float4 l = *(const float4*)(hls + (size_t)s * 16 + o4 * 4);
    float* om = out + (size_t)d * 16 + o4 * 4;
    float* ol = out + (size_t)NN * 16 + (size_t)d * 16 + o4 * 4;
    atomicAdd(om + 0, m.x * norm);
    atomicAdd(om + 1, m.y * norm);
    atomicAdd(om + 2, m.z * norm);
    atomicAdd(om + 3, m.w * norm);
    atomicAdd(ol + 0, l.x * norm);
    atomicAdd(ol + 1, l.y * norm);
    atomicAdd(ol + 2, l.z * norm);
    atomicAdd(ol + 3, l.w * norm);
}

extern "C" void kernel_launch(void* const* d_in, const int* in_sizes, int n_in,
                              void* d_out, int out_size, void* d_ws, size_t ws_size,
                              hipStream_t stream) {
    const float* x     = (const float*)d_in[0];
    const int*   ei    = (const int*)d_in[1];
    const float* ea    = (const float*)d_in[2];
    const float* nn1_w = (const float*)d_in[3];
    const float* nn1_b = (const float*)d_in[4];
    const float* root1 = (const float*)d_in[5];
    const float* bias1 = (const float*)d_in[6];
    const float* nn2_w = (const float*)d_in[7];
    const float* nn2_b = (const float*)d_in[8];
    const float* root2 = (const float*)d_in[9];
    const float* bias2 = (const float*)d_in[10];
    const float* mu_w  = (const float*)d_in[11];
    const float* mu_b  = (const float*)d_in[12];
    const float* ls_w  = (const float*)d_in[13];
    const float* ls_b  = (const float*)d_in[14];
    float* out = (float*)d_out;

    // Workspace (floats), all region starts multiple of 4 floats:
    float* W    = (float*)d_ws;
    float* Wp1  = W;                   //    30,720
    float* Wp2  = Wp1 + 30720;         //    15,360
    float* T1   = Wp2 + 15360;         // 3,932,160
    float* T2   = T1 + 3932160;        // 2,621,440
    float* agg1 = T2 + 2621440;        //   393,216  <- zero region start
    float* agg2 = agg1 + 393216;       //   262,144
    float* deg  = agg2 + 262144;       //     8,192  (zero region = 663,552 floats)
    float* hmu  = deg + 8192;          //   131,072
    float* hls  = hmu + 131072;        //   131,072
    float* dinv = hls + 131072;        //     8,192
    // total ~30 MB

    k_pre<<<dim3(828), dim3(256), 0, stream>>>(nn1_w, nn1_b, root1,
                                               nn2_w, nn2_b, root2,
                                               Wp1, Wp2, agg1);
    k_T1<<<dim3(480), dim3(256), 0, stream>>>(x, Wp1, T1);
    k_edge1<<<dim3((EE * 12) / 256), dim3(256), 0, stream>>>(ei, ea, T1, agg1);
    k_T2<<<dim3(320), dim3(256), 0, stream>>>(agg1, T1, bias1, Wp2, T2);
    k_edge2<<<dim3((EE * 8) / 256), dim3(256), 0, stream>>>(ei, ea, T2, agg2, deg);
    k_post<<<dim3(NN / 8), dim3(256), 0, stream>>>(agg2, T2, bias2, mu_w, mu_b,
                                                   ls_w, ls_b, deg, hmu, hls, dinv, out);
    k_gcn_edge<<<dim3((EE * 4) / 256), dim3(256), 0, stream>>>(ei, hmu, hls, dinv, out);
}

// Round 3
// 204.144 us; speedup vs baseline: 1.3456x; 1.3456x over previous
//
#include <hip/hip_runtime.h>

#define NN 8192
#define EE 65536

// ---------------------------------------------------------------------------
// k_pre: zero cnt[8192] + pack Wf1 = concat(nn1_w, nn1_b, root1) [640x48]
//        and Wf2 = concat(nn2_w, nn2_b, root2) [480x32]. All three sources
//        are already in the exact row order needed (k = f*64+i etc).
// grid 212*256 = 54272 = 8192 + 30720 + 15360
// ---------------------------------------------------------------------------
__global__ __launch_bounds__(256) void k_pre(const float* __restrict__ w1,
                                             const float* __restrict__ b1,
                                             const float* __restrict__ r1,
                                             const float* __restrict__ w2,
                                             const float* __restrict__ b2,
                                             const float* __restrict__ r2,
                                             float* __restrict__ Wf1,
                                             float* __restrict__ Wf2,
                                             int* __restrict__ cnt) {
    int t = blockIdx.x * 256 + threadIdx.x;
    if (t < 8192) { cnt[t] = 0; return; }
    t -= 8192;
    if (t < 30720) {
        float v;
        if (t < 24576)      v = w1[t];
        else if (t < 27648) v = b1[t - 24576];
        else                v = r1[t - 27648];
        Wf1[t] = v;
        return;
    }
    t -= 30720;
    float v;
    if (t < 12288)      v = w2[t];
    else if (t < 13824) v = b2[t - 12288];
    else                v = r2[t - 13824];
    Wf2[t] = v;
}

__global__ __launch_bounds__(256) void k_hist(const int* __restrict__ ei,
                                              int* __restrict__ cnt) {
    int e = blockIdx.x * 256 + threadIdx.x;
    atomicAdd(&cnt[ei[EE + e]], 1);
}

// Single-block scan of 8192 degree counts -> row_ptr[8193] and cursor copy.
__global__ __launch_bounds__(1024) void k_scan(const int* __restrict__ cnt,
                                               int* __restrict__ row_ptr,
                                               int* __restrict__ cursor) {
    __shared__ int sd[1024];
    const int t = threadIdx.x;
    const int base = t * 8;
    int v[8];
    int s = 0;
#pragma unroll
    for (int j = 0; j < 8; j++) { v[j] = cnt[base + j]; s += v[j]; }
    sd[t] = s;
    __syncthreads();
    for (int off = 1; off < 1024; off <<= 1) {
        int a = sd[t];
        int b = (t >= off) ? sd[t - off] : 0;
        __syncthreads();
        sd[t] = a + b;
        __syncthreads();
    }
    int run = sd[t] - s;  // exclusive prefix
#pragma unroll
    for (int j = 0; j < 8; j++) {
        row_ptr[base + j] = run;
        cursor[base + j] = run;
        run += v[j];
    }
    if (t == 1023) row_ptr[8192] = run;
}

__global__ __launch_bounds__(256) void k_scatter(const int* __restrict__ ei,
                                                 int* __restrict__ cursor,
                                                 int* __restrict__ cs_e) {
    int e = blockIdx.x * 256 + threadIdx.x;
    int d = ei[EE + e];
    int slot = atomicAdd(&cursor[d], 1);
    cs_e[slot] = e;
}

// ---------------------------------------------------------------------------
// k_y1: one wave per dst node. lane = input channel i (64).
// y[f] = sum_edges ea[e,f]*x[s][i] (f<8), y[8] = sum x[s][i].
// Z1 row [d][640] = [y0..y8 (576), x_d (64)]. Coalesced writes, no atomics.
// ---------------------------------------------------------------------------
__global__ __launch_bounds__(256) void k_y1(const int* __restrict__ ei,
                                            const float* __restrict__ ea,
                                            const float* __restrict__ x,
                                            const int* __restrict__ row_ptr,
                                            const int* __restrict__ cs_e,
                                            float* __restrict__ Z1) {
    const int lane = threadIdx.x & 63;
    const int d = blockIdx.x * 4 + (threadIdx.x >> 6);
    float y[9];
#pragma unroll
    for (int f = 0; f < 9; f++) y[f] = 0.f;
    const int rp0 = row_ptr[d], rp1 = row_ptr[d + 1];
    for (int idx = rp0; idx < rp1; idx++) {
        int e = cs_e[idx];
        int s = ei[e];
        float xv = x[(size_t)s * 64 + lane];
        float4 a0 = *(const float4*)(ea + (size_t)e * 8);
        float4 a1 = *(const float4*)(ea + (size_t)e * 8 + 4);
        y[0] += a0.x * xv; y[1] += a0.y * xv; y[2] += a0.z * xv; y[3] += a0.w * xv;
        y[4] += a1.x * xv; y[5] += a1.y * xv; y[6] += a1.z * xv; y[7] += a1.w * xv;
        y[8] += xv;
    }
    float* zr = Z1 + (size_t)d * 640;
#pragma unroll
    for (int f = 0; f < 9; f++) zr[f * 64 + lane] = y[f];
    zr[576 + lane] = x[(size_t)d * 64 + lane];
}

// ---------------------------------------------------------------------------
// k_g1: h1 = relu(Z1[8192x640] @ Wf1[640x48] + bias1). Tile 32 nodes x 48
// cols per block (256 blocks), 192 threads, thread tile 4n x 2c, K-chunk 64.
// LDS: Zs[k][n] 8 KB + Ws[k][c] 12 KB.
// ---------------------------------------------------------------------------
__global__ __launch_bounds__(192) void k_g1(const float* __restrict__ Z1,
                                            const float* __restrict__ Wf1,
                                            const float* __restrict__ bias1,
                                            float* __restrict__ h1) {
    __shared__ float Zs[64 * 32];
    __shared__ float Ws[64 * 48];
    const int t = threadIdx.x;
    const int nb = blockIdx.x * 32;
    const int n0 = (t & 7) * 4;
    const int c0 = (t >> 3) * 2;
    float acc[4][2] = {{0.f, 0.f}, {0.f, 0.f}, {0.f, 0.f}, {0.f, 0.f}};
    for (int k0 = 0; k0 < 640; k0 += 64) {
        for (int idx = t; idx < 512; idx += 192) {
            int nn = idx >> 4, kk = (idx & 15) * 4;
            float4 v = *(const float4*)(Z1 + (size_t)(nb + nn) * 640 + k0 + kk);
            Zs[(kk + 0) * 32 + nn] = v.x;
            Zs[(kk + 1) * 32 + nn] = v.y;
            Zs[(kk + 2) * 32 + nn] = v.z;
            Zs[(kk + 3) * 32 + nn] = v.w;
        }
        for (int idx = t; idx < 768; idx += 192) {
            *(float4*)(Ws + idx * 4) = *(const float4*)(Wf1 + (size_t)k0 * 48 + idx * 4);
        }
        __syncthreads();
#pragma unroll 8
        for (int k = 0; k < 64; k++) {
            float4 a = *(const float4*)(Zs + k * 32 + n0);
            float2 w = *(const float2*)(Ws + k * 48 + c0);
            acc[0][0] += a.x * w.x; acc[0][1] += a.x * w.y;
            acc[1][0] += a.y * w.x; acc[1][1] += a.y * w.y;
            acc[2][0] += a.z * w.x; acc[2][1] += a.z * w.y;
            acc[3][0] += a.w * w.x; acc[3][1] += a.w * w.y;
        }
        __syncthreads();
    }
    float2 b = *(const float2*)(bias1 + c0);
#pragma unroll
    for (int i = 0; i < 4; i++) {
        int n = nb + n0 + i;
        float2 o;
        o.x = fmaxf(acc[i][0] + b.x, 0.f);
        o.y = fmaxf(acc[i][1] + b.y, 0.f);
        *(float2*)(h1 + (size_t)n * 48 + c0) = o;
    }
}

// ---------------------------------------------------------------------------
// k_y2: one wave per dst node, lanes 0..47 = h1 channel.
// Z2 row [d][480] = [y0..y8 (432), h1_d (48)].
// ---------------------------------------------------------------------------
__global__ __launch_bounds__(256) void k_y2(const int* __restrict__ ei,
                                            const float* __restrict__ ea,
                                            const float* __restrict__ h1,
                                            const int* __restrict__ row_ptr,
                                            const int* __restrict__ cs_e,
                                            float* __restrict__ Z2) {
    const int lane = threadIdx.x & 63;
    const int d = blockIdx.x * 4 + (threadIdx.x >> 6);
    if (lane >= 48) return;
    float y[9];
#pragma unroll
    for (int f = 0; f < 9; f++) y[f] = 0.f;
    const int rp0 = row_ptr[d], rp1 = row_ptr[d + 1];
    for (int idx = rp0; idx < rp1; idx++) {
        int e = cs_e[idx];
        int s = ei[e];
        float hv = h1[(size_t)s * 48 + lane];
        float4 a0 = *(const float4*)(ea + (size_t)e * 8);
        float4 a1 = *(const float4*)(ea + (size_t)e * 8 + 4);
        y[0] += a0.x * hv; y[1] += a0.y * hv; y[2] += a0.z * hv; y[3] += a0.w * hv;
        y[4] += a1.x * hv; y[5] += a1.y * hv; y[6] += a1.z * hv; y[7] += a1.w * hv;
        y[8] += hv;
    }
    float* zr = Z2 + (size_t)d * 480;
#pragma unroll
    for (int f = 0; f < 9; f++) zr[f * 48 + lane] = y[f];
    zr[432 + lane] = h1[(size_t)d * 48 + lane];
}

// ---------------------------------------------------------------------------
// k_g2: h2 = relu(Z2 @ Wf2 + bias2); then heads hcat=[h2@mu_w, h2@ls_w],
// dinv, and out init (self-loop + bias). Tile 32 nodes, 256 threads,
// thread tile 2n x 2c, K-chunk 48.
// ---------------------------------------------------------------------------
__global__ __launch_bounds__(256) void k_g2(const float* __restrict__ Z2,
                                            const float* __restrict__ Wf2,
                                            const float* __restrict__ bias2,
                                            const float* __restrict__ mu_w,
                                            const float* __restrict__ mu_b,
                                            const float* __restrict__ ls_w,
                                            const float* __restrict__ ls_b,
                                            const int* __restrict__ row_ptr,
                                            float* __restrict__ hcat,
                                            float* __restrict__ dinv,
                                            float* __restrict__ out) {
    __shared__ float Zs[48 * 32];
    __shared__ float Ws[48 * 32];
    __shared__ float h2s[32 * 33];
    const int t = threadIdx.x;
    const int nb = blockIdx.x * 32;
    const int n0 = (t & 15) * 2;
    const int c0 = (t >> 4) * 2;
    float acc[2][2] = {{0.f, 0.f}, {0.f, 0.f}};
    for (int k0 = 0; k0 < 480; k0 += 48) {
        for (int idx = t; idx < 384; idx += 256) {
            int nn = idx / 12, kk = (idx % 12) * 4;
            float4 v = *(const float4*)(Z2 + (size_t)(nb + nn) * 480 + k0 + kk);
            Zs[(kk + 0) * 32 + nn] = v.x;
            Zs[(kk + 1) * 32 + nn] = v.y;
            Zs[(kk + 2) * 32 + nn] = v.z;
            Zs[(kk + 3) * 32 + nn] = v.w;
        }
        for (int idx = t; idx < 384; idx += 256) {
            *(float4*)(Ws + idx * 4) = *(const float4*)(Wf2 + (size_t)k0 * 32 + idx * 4);
        }
        __syncthreads();
#pragma unroll 8
        for (int k = 0; k < 48; k++) {
            float2 a = *(const float2*)(Zs + k * 32 + n0);
            float2 w = *(const float2*)(Ws + k * 32 + c0);
            acc[0][0] += a.x * w.x; acc[0][1] += a.x * w.y;
            acc[1][0] += a.y * w.x; acc[1][1] += a.y * w.y;
        }
        __syncthreads();
    }
    float2 b2v = *(const float2*)(bias2 + c0);
    h2s[(n0 + 0) * 33 + c0]     = fmaxf(acc[0][0] + b2v.x, 0.f);
    h2s[(n0 + 0) * 33 + c0 + 1] = fmaxf(acc[0][1] + b2v.y, 0.f);
    h2s[(n0 + 1) * 33 + c0]     = fmaxf(acc[1][0] + b2v.x, 0.f);
    h2s[(n0 + 1) * 33 + c0 + 1] = fmaxf(acc[1][1] + b2v.y, 0.f);
    __syncthreads();
    // heads: 32 nodes x 32 outputs (16 mu + 16 ls), 8 threads/node, 4 outs each
    const int n = t >> 3;
    const int q = t & 7;
    const float* wh = (q < 4) ? mu_w : ls_w;
    const float* bh = (q < 4) ? mu_b : ls_b;
    const int base_o = (q & 3) * 4;
    float a4[4] = {0.f, 0.f, 0.f, 0.f};
#pragma unroll 8
    for (int i = 0; i < 32; i++) {
        float v = h2s[n * 33 + i];
        a4[0] += v * wh[i * 16 + base_o + 0];
        a4[1] += v * wh[i * 16 + base_o + 1];
        a4[2] += v * wh[i * 16 + base_o + 2];
        a4[3] += v * wh[i * 16 + base_o + 3];
    }
    const int d = nb + n;
    const int degi = row_ptr[d + 1] - row_ptr[d] + 1;
    const float invd = 1.f / (float)degi;
    if (q == 0) dinv[d] = rsqrtf((float)degi);
    const size_t outbase = (q < 4) ? 0 : (size_t)NN * 16;
    const int hoff = (q < 4) ? 0 : 16;
#pragma unroll
    for (int j = 0; j < 4; j++) {
        int col = base_o + j;
        hcat[(size_t)d * 32 + hoff + col] = a4[j];
        out[outbase + (size_t)d * 16 + col] = a4[j] * invd + bh[col];
    }
}

// ---------------------------------------------------------------------------
// k_gcn: per dst node, 32 lanes (16 mu + 16 ls): neighbor sum of
// hcat[s]*dinv[s], scaled by dinv[d], added into out. No atomics.
// ---------------------------------------------------------------------------
__global__ __launch_bounds__(256) void k_gcn(const int* __restrict__ ei,
                                             const int* __restrict__ row_ptr,
                                             const int* __restrict__ cs_e,
                                             const float* __restrict__ hcat,
                                             const float* __restrict__ dinv,
                                             float* __restrict__ out) {
    const int t = threadIdx.x;
    const int lane32 = t & 31;
    const int d = blockIdx.x * 8 + (t >> 5);
    float acc = 0.f;
    const int rp0 = row_ptr[d], rp1 = row_ptr[d + 1];
    for (int idx = rp0; idx < rp1; idx++) {
        int e = cs_e[idx];
        int s = ei[e];
        acc += hcat[(size_t)s * 32 + lane32] * dinv[s];
    }
    acc *= dinv[d];
    const int col = lane32 & 15;
    const size_t addr = (lane32 < 16) ? ((size_t)d * 16 + col)
                                      : ((size_t)NN * 16 + (size_t)d * 16 + col);
    out[addr] += acc;
}

extern "C" void kernel_launch(void* const* d_in, const int* in_sizes, int n_in,
                              void* d_out, int out_size, void* d_ws, size_t ws_size,
                              hipStream_t stream) {
    const float* x     = (const float*)d_in[0];
    const int*   ei    = (const int*)d_in[1];
    const float* ea    = (const float*)d_in[2];
    const float* nn1_w = (const float*)d_in[3];
    const float* nn1_b = (const float*)d_in[4];
    const float* root1 = (const float*)d_in[5];
    const float* bias1 = (const float*)d_in[6];
    const float* nn2_w = (const float*)d_in[7];
    const float* nn2_b = (const float*)d_in[8];
    const float* root2 = (const float*)d_in[9];
    const float* bias2 = (const float*)d_in[10];
    const float* mu_w  = (const float*)d_in[11];
    const float* mu_b  = (const float*)d_in[12];
    const float* ls_w  = (const float*)d_in[13];
    const float* ls_b  = (const float*)d_in[14];
    float* out = (float*)d_out;

    // Workspace layout (4-byte units, all segment starts 16B-aligned)
    float* W      = (float*)d_ws;
    float* Wf1    = W;                    //    30,720
    float* Wf2    = Wf1 + 30720;          //    15,360
    int*   cnt    = (int*)(Wf2 + 15360);  //     8,192
    int*   row_ptr= cnt + 8192;           //     8,196 (8193 used)
    int*   cursor = row_ptr + 8196;       //     8,192
    int*   cs_e   = cursor + 8192;        //    65,536
    float* Z1     = (float*)(cs_e + 65536);    // 5,242,880
    float* Z2     = Z1 + 5242880;              // 3,932,160
    float* h1     = Z2 + 3932160;              //   393,216
    float* hcat   = h1 + 393216;               //   262,144
    float* dinv   = hcat + 262144;             //     8,192
    // total ~40 MB

    k_pre<<<dim3(212), dim3(256), 0, stream>>>(nn1_w, nn1_b, root1,
                                               nn2_w, nn2_b, root2,
                                               Wf1, Wf2, cnt);
    k_hist<<<dim3(256), dim3(256), 0, stream>>>(ei, cnt);
    k_scan<<<dim3(1), dim3(1024), 0, stream>>>(cnt, row_ptr, cursor);
    k_scatter<<<dim3(256), dim3(256), 0, stream>>>(ei, cursor, cs_e);
    k_y1<<<dim3(2048), dim3(256), 0, stream>>>(ei, ea, x, row_ptr, cs_e, Z1);
    k_g1<<<dim3(256), dim3(192), 0, stream>>>(Z1, Wf1, bias1, h1);
    k_y2<<<dim3(2048), dim3(256), 0, stream>>>(ei, ea, h1, row_ptr, cs_e, Z2);
    k_g2<<<dim3(256), dim3(256), 0, stream>>>(Z2, Wf2, bias2, mu_w, mu_b,
                                              ls_w, ls_b, row_ptr, hcat, dinv, out);
    k_gcn<<<dim3(1024), dim3(256), 0, stream>>>(ei, row_ptr, cs_e, hcat, dinv, out);
}